// Round 11
// baseline (20759.729 us; speedup 1.0000x reference)
//
#include <hip/hip_runtime.h>
#include <cstdint>
#include <cstddef>

// ---------------- problem constants ----------------
namespace {
constexpr int Bb = 8, Ss = 2048, Ee = 256, Hh = 256, G4 = 1024, Tt = 12;
constexpr int NTOK = Bb * Ss;              // 16384 rows
constexpr int NC = 256, LCH = 64;          // viterbi chunking: 256 chunks x 64 steps
constexpr float FNEG = -10000.0f;
constexpr int START_TAG = 10, STOP_TAG = 11;

// ---------------- workspace layout (bytes) ----------------
constexpr size_t OFF_XS    = 0;                         // [16384][256] f32 gathered embeddings
constexpr size_t SZ_XS     = (size_t)NTOK * Ee * 4;
constexpr size_t OFF_WT    = OFF_XS + SZ_XS;            // [2][256][1024] f32 w_ih transposed
constexpr size_t SZ_WT     = (size_t)2 * Ee * G4 * 4;
constexpr size_t OFF_XPF   = OFF_WT + SZ_WT;            // [2048][8][1024] f32 x-proj fwd (bias folded)
constexpr size_t SZ_XP     = (size_t)Ss * Bb * G4 * 4;
constexpr size_t OFF_XPB   = OFF_XPF + SZ_XP;
constexpr size_t OFF_HF    = OFF_XPB + SZ_XP;           // [2048][8][256] f32 fwd hidden history
constexpr size_t SZ_H      = (size_t)Ss * Bb * Hh * 4;
constexpr size_t OFF_HB    = OFF_HF + SZ_H;
constexpr size_t OFF_FEATS = OFF_HB + SZ_H;             // [16384][12] f32
constexpr size_t SZ_FEATS  = (size_t)NTOK * Tt * 4;
constexpr size_t OFF_PMAT  = OFF_FEATS + SZ_FEATS;      // [256][144] f32 chunk max-plus mats
constexpr size_t SZ_PMAT   = (size_t)NC * 144 * 4;
constexpr size_t OFF_FVIN  = OFF_PMAT + SZ_PMAT;        // [256][12] f32 chunk-entry fv
constexpr size_t SZ_FVIN   = (size_t)NC * Tt * 4;
constexpr size_t OFF_BPTR  = OFF_FVIN + SZ_FVIN;        // [16384] u64 packed 12x4bit backptrs
constexpr size_t SZ_BPTR   = (size_t)NTOK * 8;
constexpr size_t OFF_CMAP  = OFF_BPTR + SZ_BPTR;        // [256][12] int chunk composed maps
constexpr size_t SZ_CMAP   = (size_t)NC * Tt * 4;
constexpr size_t OFF_EVEC  = OFF_CMAP + SZ_CMAP;        // [256] int tag at chunk-end
constexpr size_t SZ_EVEC   = (size_t)NC * 4;
constexpr size_t OFF_BEST  = OFF_EVEC + SZ_EVEC;        // [1] int
constexpr size_t SZ_BEST   = 256;
constexpr size_t OFF_HD    = OFF_BEST + SZ_BEST;        // (legacy, unused)
constexpr size_t SZ_HD     = (size_t)2 * 2 * 2048 * 8;
constexpr size_t OFF_EPOCH = OFF_HD + SZ_HD;            // (legacy, unused)
constexpr size_t SZ_EPOCH  = 256;
constexpr size_t WS_NEED   = OFF_EPOCH + SZ_EPOCH;      // ~179 MB (unchanged)

// w_hh^T [2][256][1024] (2 MB) lives in the XS region, which is dead after
// k_inproj consumes xs. Written by a second k_transpose dispatch that runs
// AFTER k_inproj (stream-ordered), read by k_lstm via normal loads.
constexpr size_t OFF_WHT   = OFF_XS;
static_assert(2 * 256 * 1024 * 4 <= SZ_XS, "whhT fits in xs region");

// k_lstm weight tiers (per 1024-thread WG, one WG per (dir,batch) chain):
//   KR rows of W_hh^T in VGPRs  (1 float/thread/row -> KR VGPRs)
//   KL rows in LDS              (4 KB/row)
//   KS rows streamed from L2    (576 KB/step, L2-resident read-only)
// R15 vs R14: R12-R14 all pinned at ~77 GB/s/CU effective stream rate
// regardless of tiering (R14: VGPR 216, time unchanged 18.8->18.7ms) =>
// the limiter is LOAD ISSUE PARALLELISM at 4 waves/CU, not spill traffic.
// 1024-thread blocks give 16 waves (4/SIMD, the compiler's honored 128-reg
// regime). One column/thread makes tier-1 a scalar array: KR=76 regs + ~45
// overhead = ~121 <= 128, finally fully resident. 16 waves x in-flight
// loads should move the stream from latency-bound (~77) toward the L2
// per-CU rate (~135 GB/s, m56).
constexpr int KR = 76, KL = 36, KS = 256 - KR - KL;   // 144
static_assert(KR % 4 == 0 && KL % 4 == 0 && KS % 4 == 0, "tiers 4-aligned");

__device__ __forceinline__ float4 f4fma(float a, float4 b, float4 c) {
  c.x = fmaf(a, b.x, c.x); c.y = fmaf(a, b.y, c.y);
  c.z = fmaf(a, b.z, c.z); c.w = fmaf(a, b.w, c.w);
  return c;
}
}  // namespace

// ---------------- gather embeddings: xs[r=t*8+b][k] = emb[sentence[b][t]][k] ----------------
__global__ __launch_bounds__(256) void k_gather(const int* __restrict__ sent,
                                                const float* __restrict__ emb,
                                                float* __restrict__ xs) {
  int rr = threadIdx.x >> 3, p = threadIdx.x & 7;
  int r = blockIdx.x * 32 + rr;
  int tg = r >> 3, bg = r & 7;
  int tok = sent[bg * Ss + tg];
  const float4* src = (const float4*)(emb + (size_t)tok * Ee) + p * 8;
  float4* dst = (float4*)(xs + (size_t)r * Ee) + p * 8;
#pragma unroll
  for (int i = 0; i < 8; ++i) dst[i] = src[i];
}

// ---------------- transpose [1024][256] -> [k][n] (used for w_ih AND w_hh) ----------------
__global__ __launch_bounds__(256) void k_transpose(const float* __restrict__ w_f,
                                                   const float* __restrict__ w_b,
                                                   float* __restrict__ wT) {
  int idx = blockIdx.x * 256 + threadIdx.x;
  if (idx >= 2 * Ee * G4) return;
  int d = idx >> 18;
  int rem = idx & 262143;
  int k = rem >> 10, n = rem & 1023;
  const float* w = d ? w_b : w_f;
  wT[idx] = w[n * Ee + k];
}

// ---------------- input projection GEMM: xp[r][n] = xs[r][:] . w_ih[n][:] + bias[n] ----------------
__global__ __launch_bounds__(256) void k_inproj(const float* __restrict__ xs,
                                                const float* __restrict__ wT,
                                                const float* __restrict__ b_f,
                                                const float* __restrict__ b_b,
                                                float* __restrict__ xpf,
                                                float* __restrict__ xpb) {
  const int dir = blockIdx.z;
  const float* wTd = wT + (size_t)dir * (Ee * G4);
  const float* bv = dir ? b_b : b_f;
  float* xp = dir ? xpb : xpf;
  const int rg = threadIdx.x >> 5, cg = threadIdx.x & 31;
  const int rbase = blockIdx.x * 32 + rg * 4;
  const int c0 = blockIdx.y * 128 + cg * 4;
  const float4* ap0 = (const float4*)(xs + (size_t)(rbase + 0) * Ee);
  const float4* ap1 = (const float4*)(xs + (size_t)(rbase + 1) * Ee);
  const float4* ap2 = (const float4*)(xs + (size_t)(rbase + 2) * Ee);
  const float4* ap3 = (const float4*)(xs + (size_t)(rbase + 3) * Ee);
  float4 acc0 = {0,0,0,0}, acc1 = {0,0,0,0}, acc2 = {0,0,0,0}, acc3 = {0,0,0,0};
#pragma unroll 4
  for (int k4 = 0; k4 < 64; ++k4) {
    float4 a0 = ap0[k4], a1 = ap1[k4], a2 = ap2[k4], a3 = ap3[k4];
    const float* wb = wTd + (size_t)(k4 * 4) * G4 + c0;
    float4 b0 = *(const float4*)(wb);
    float4 b1 = *(const float4*)(wb + G4);
    float4 b2 = *(const float4*)(wb + 2 * G4);
    float4 b3 = *(const float4*)(wb + 3 * G4);
    acc0 = f4fma(a0.x, b0, acc0); acc0 = f4fma(a0.y, b1, acc0);
    acc0 = f4fma(a0.z, b2, acc0); acc0 = f4fma(a0.w, b3, acc0);
    acc1 = f4fma(a1.x, b0, acc1); acc1 = f4fma(a1.y, b1, acc1);
    acc1 = f4fma(a1.z, b2, acc1); acc1 = f4fma(a1.w, b3, acc1);
    acc2 = f4fma(a2.x, b0, acc2); acc2 = f4fma(a2.y, b1, acc2);
    acc2 = f4fma(a2.z, b2, acc2); acc2 = f4fma(a2.w, b3, acc2);
    acc3 = f4fma(a3.x, b0, acc3); acc3 = f4fma(a3.y, b1, acc3);
    acc3 = f4fma(a3.z, b2, acc3); acc3 = f4fma(a3.w, b3, acc3);
  }
  float4 bias = *(const float4*)(bv + c0);
  acc0.x += bias.x; acc0.y += bias.y; acc0.z += bias.z; acc0.w += bias.w;
  acc1.x += bias.x; acc1.y += bias.y; acc1.z += bias.z; acc1.w += bias.w;
  acc2.x += bias.x; acc2.y += bias.y; acc2.z += bias.z; acc2.w += bias.w;
  acc3.x += bias.x; acc3.y += bias.y; acc3.z += bias.z; acc3.w += bias.w;
  *(float4*)(xp + (size_t)(rbase + 0) * G4 + c0) = acc0;
  *(float4*)(xp + (size_t)(rbase + 1) * G4 + c0) = acc1;
  *(float4*)(xp + (size_t)(rbase + 2) * G4 + c0) = acc2;
  *(float4*)(xp + (size_t)(rbase + 3) * G4 + c0) = acc3;
}

// ---------------- persistent bidirectional LSTM: BATCH-SPLIT, NO EXCHANGE ----------------
// 16 WGs, one per (dir, batch) chain, ZERO inter-WG communication (R4-R11:
// all cross-WG coherence paths bottom out at ~5-6.5us/step on this machine).
// h lives in LDS, c in registers; per-step sync is two __syncthreads.
// Weights 3-tiered: VGPR / LDS / L2-stream (see tier comment above).
// R15 thread map: 1024 threads; thread t owns output column n=t of z[1024]
// (PyTorch gate order: rows 0-255=i, 256-511=f, 512-767=g, 768-1023=o).
// Gate phase: threads t<256 own channel t.
__global__ __launch_bounds__(1024, 1) void k_lstm(
    const float* __restrict__ whhT,
    const float* __restrict__ h0, const float* __restrict__ c0,
    const float* __restrict__ xpf, const float* __restrict__ xpb,
    float* __restrict__ hist_f, float* __restrict__ hist_b) {
  __shared__ __align__(16) float h_lds[256];
  __shared__ __align__(16) float z_lds[1024];
  __shared__ __align__(16) float wlds[KL][1024];

  const int wg = blockIdx.x, dir = wg >> 3, b = wg & 7;
  const int t = threadIdx.x;
  const float* WT = whhT + (size_t)dir * (256 * 1024);
  const float* xp = dir ? xpb : xpf;
  float* hist = dir ? hist_b : hist_f;

  // tier 1: KR rows in registers (1 float per thread per row)
  float wreg[KR];
#pragma unroll
  for (int k = 0; k < KR; ++k)
    wreg[k] = WT[(size_t)k * 1024 + t];
  // tier 2: KL rows into LDS
  for (int i = t; i < KL * 1024; i += 1024)
    wlds[i >> 10][i & 1023] = WT[(size_t)(KR + (i >> 10)) * 1024 + (i & 1023)];
  // state
  if (t < 256) h_lds[t] = h0[dir * 2048 + b * 256 + t];
  float c_reg = (t < 256) ? c0[dir * 2048 + b * 256 + t] : 0.0f;
  __syncthreads();

  const float* WS = WT + (size_t)(KR + KL) * 1024;  // tier 3: streamed rows

  for (int s = 0; s < Ss; ++s) {
    const int tg = dir ? (Ss - 1 - s) : s;
    // xp prefetch (h-independent)
    float acc0 = xp[(size_t)tg * 8192 + b * 1024 + t];
    float acc1 = 0.0f;  // second accumulator breaks the serial FMA chain
    // tier 1: registers
#pragma unroll
    for (int k4 = 0; k4 < KR / 4; ++k4) {
      float4 h4 = *(const float4*)&h_lds[k4 * 4];
      acc0 = fmaf(h4.x, wreg[k4 * 4 + 0], acc0);
      acc1 = fmaf(h4.y, wreg[k4 * 4 + 1], acc1);
      acc0 = fmaf(h4.z, wreg[k4 * 4 + 2], acc0);
      acc1 = fmaf(h4.w, wreg[k4 * 4 + 3], acc1);
    }
    // tier 2: LDS
#pragma unroll
    for (int k4 = 0; k4 < KL / 4; ++k4) {
      float4 h4 = *(const float4*)&h_lds[KR + k4 * 4];
      float w0 = wlds[k4 * 4 + 0][t];
      float w1 = wlds[k4 * 4 + 1][t];
      float w2 = wlds[k4 * 4 + 2][t];
      float w3 = wlds[k4 * 4 + 3][t];
      acc0 = fmaf(h4.x, w0, acc0);
      acc1 = fmaf(h4.y, w1, acc1);
      acc0 = fmaf(h4.z, w2, acc0);
      acc1 = fmaf(h4.w, w3, acc1);
    }
    // tier 3: streamed from L2 (16 waves keep the load pipe full)
#pragma unroll 4
    for (int k4 = 0; k4 < KS / 4; ++k4) {
      const float* wp = WS + (size_t)(k4 * 4) * 1024 + t;
      float w0 = wp[0];
      float w1 = wp[1024];
      float w2 = wp[2048];
      float w3 = wp[3072];
      float4 h4 = *(const float4*)&h_lds[KR + KL + k4 * 4];
      acc0 = fmaf(h4.x, w0, acc0);
      acc1 = fmaf(h4.y, w1, acc1);
      acc0 = fmaf(h4.z, w2, acc0);
      acc1 = fmaf(h4.w, w3, acc1);
    }
    z_lds[t] = acc0 + acc1;
    __syncthreads();  // B1: z complete; all h_lds reads of this step done
    if (t < 256) {
      float zi = z_lds[t], zf = z_lds[256 + t];
      float zg = z_lds[512 + t], zo = z_lds[768 + t];
      float iv = 1.0f / (1.0f + expf(-zi));
      float fv = 1.0f / (1.0f + expf(-zf));
      float gv = tanhf(zg);
      float ov = 1.0f / (1.0f + expf(-zo));
      c_reg = fv * c_reg + iv * gv;
      float hv = ov * tanhf(c_reg);
      h_lds[t] = hv;
      hist[(size_t)tg * 2048 + b * 256 + t] = hv;
    }
    __syncthreads();  // B2: h_{s} ready for next step
  }
}

// ---------------- feats = [hf|hb] @ W_out^T + b_out ----------------
__global__ __launch_bounds__(256) void k_feats(const float* __restrict__ hist_f,
                                               const float* __restrict__ hist_b,
                                               const float* __restrict__ Wout,
                                               const float* __restrict__ bout,
                                               float* __restrict__ feats) {
  __shared__ float wsh[Tt * 512];
  __shared__ float bsh[Tt];
  for (int i = threadIdx.x; i < Tt * 512; i += 256) wsh[i] = Wout[i];
  if (threadIdx.x < Tt) bsh[threadIdx.x] = bout[threadIdx.x];
  __syncthreads();
  int r = blockIdx.x * 256 + threadIdx.x;
  int bq = r >> 11, sq = r & 2047;
  const float4* hf4 = (const float4*)(hist_f + (size_t)sq * 2048 + bq * Hh);
  const float4* hb4 = (const float4*)(hist_b + (size_t)sq * 2048 + bq * Hh);
  float acc[Tt];
#pragma unroll
  for (int j = 0; j < Tt; ++j) acc[j] = bsh[j];
  for (int k4 = 0; k4 < 64; ++k4) {
    float4 x = hf4[k4];
#pragma unroll
    for (int j = 0; j < Tt; ++j) {
      float4 w = *(const float4*)&wsh[j * 512 + k4 * 4];
      acc[j] = fmaf(x.x, w.x, fmaf(x.y, w.y, fmaf(x.z, w.z, fmaf(x.w, w.w, acc[j]))));
    }
  }
  for (int k4 = 0; k4 < 64; ++k4) {
    float4 x = hb4[k4];
#pragma unroll
    for (int j = 0; j < Tt; ++j) {
      float4 w = *(const float4*)&wsh[j * 512 + 256 + k4 * 4];
      acc[j] = fmaf(x.x, w.x, fmaf(x.y, w.y, fmaf(x.z, w.z, fmaf(x.w, w.w, acc[j]))));
    }
  }
#pragma unroll
  for (int j = 0; j < Tt; ++j) feats[(size_t)r * Tt + j] = acc[j];
}

// ---------------- Viterbi phase 1: per-chunk max-plus matrix product ----------------
__global__ __launch_bounds__(192) void k_vit_chunkmat(const float* __restrict__ feats,
                                                      const float* __restrict__ trans,
                                                      float* __restrict__ pmat) {
  __shared__ float R[2][144];
  __shared__ float fe[LCH * Tt];
  __shared__ float ts[144];
  const int t = threadIdx.x, c = blockIdx.x;
  for (int i = t; i < LCH * Tt; i += 192) fe[i] = feats[(size_t)c * LCH * Tt + i];
  if (t < 144) ts[t] = trans[t];
  __syncthreads();
  int j = 0, k = 0;
  float trow[12];
  if (t < 144) {
    j = t / 12; k = t - j * 12;
#pragma unroll
    for (int m = 0; m < 12; ++m) trow[m] = ts[j * 12 + m];
    R[0][t] = ts[t] + fe[j];  // A_{t0}
  }
  __syncthreads();
  for (int i = 1; i < LCH; ++i) {
    int p = (i - 1) & 1;
    if (t < 144) {
      float m = trow[0] + R[p][k];
#pragma unroll
      for (int mm = 1; mm < 12; ++mm) m = fmaxf(m, trow[mm] + R[p][mm * 12 + k]);
      R[p ^ 1][t] = m + fe[i * 12 + j];
    }
    __syncthreads();
  }
  if (t < 144) pmat[(size_t)c * 144 + t] = R[(LCH - 1) & 1][t];
}

// ---------------- Viterbi phase 2: sequential scan over chunk matrices ----------------
__global__ __launch_bounds__(192) void k_vit_scan(const float* __restrict__ pmat,
                                                  const float* __restrict__ trans,
                                                  float* __restrict__ fvin,
                                                  float* __restrict__ dout,
                                                  int* __restrict__ best) {
  __shared__ float fv[12];
  __shared__ float sl[144];
  __shared__ float term[12];
  const int t = threadIdx.x;
  const int j = t / 12, k = t - j * 12;
  if (t < 12) fv[t] = (t == START_TAG) ? 0.0f : FNEG;
  float pv = (t < 144) ? pmat[t] : 0.0f;
  __syncthreads();
  for (int c = 0; c < NC; ++c) {
    if (t < 12) fvin[c * 12 + t] = fv[t];
    float pnext = (t < 144 && c + 1 < NC) ? pmat[(size_t)(c + 1) * 144 + t] : 0.0f;
    if (t < 144) sl[t] = pv + fv[k];
    __syncthreads();
    if (t < 12) {
      float m = sl[t * 12];
#pragma unroll
      for (int kk = 1; kk < 12; ++kk) m = fmaxf(m, sl[t * 12 + kk]);
      fv[t] = m;
    }
    __syncthreads();
    pv = pnext;
  }
  if (t < 12) term[t] = fv[t] + trans[STOP_TAG * 12 + t];
  __syncthreads();
  if (t == 0) {
    float m = term[0]; int a = 0;
    for (int q = 1; q < 12; ++q) { if (term[q] > m) { m = term[q]; a = q; } }
    dout[0] = m;
    best[0] = a;
  }
}

// ---------------- Viterbi phase 3: replay chunks -> packed backpointers ----------------
__global__ __launch_bounds__(64) void k_vit_replay(const float* __restrict__ feats,
                                                   const float* __restrict__ trans,
                                                   const float* __restrict__ fvin,
                                                   unsigned long long* __restrict__ bptr) {
  __shared__ float fe[LCH * Tt];
  __shared__ float fv[12];
  __shared__ int bpn[12];
  const int t = threadIdx.x, c = blockIdx.x;
  for (int i = t; i < LCH * Tt; i += 64) fe[i] = feats[(size_t)c * LCH * Tt + i];
  float trow[12];
  if (t < 12) {
#pragma unroll
    for (int m = 0; m < 12; ++m) trow[m] = trans[t * 12 + m];
    fv[t] = fvin[c * 12 + t];
  }
  __syncthreads();
  for (int i = 0; i < LCH; ++i) {
    float nm = 0.0f;
    if (t < 12) {
      float m = fv[0] + trow[0]; int a = 0;
#pragma unroll
      for (int k = 1; k < 12; ++k) {
        float v = fv[k] + trow[k];
        if (v > m) { m = v; a = k; }   // first-max wins, matches jnp.argmax
      }
      nm = m + fe[i * 12 + t];
      bpn[t] = a;
    }
    __syncthreads();
    if (t < 12) fv[t] = nm;
    if (t == 0) {
      unsigned long long bp = 0;
#pragma unroll
      for (int jq = 0; jq < 12; ++jq)
        bp |= (unsigned long long)(unsigned)bpn[jq] << (4 * jq);
      bptr[(size_t)c * LCH + i] = bp;
    }
    __syncthreads();
  }
}

// ---------------- backtrace phase A: compose per-chunk tag maps ----------------
__global__ __launch_bounds__(64) void k_bt_chunk(const unsigned long long* __restrict__ bptr,
                                                 int* __restrict__ cmap) {
  __shared__ unsigned long long bp[LCH];
  const int t = threadIdx.x, c = blockIdx.x;
  if (t < LCH) bp[t] = bptr[(size_t)c * LCH + t];
  __syncthreads();
  if (t < 12) {
    int v = t;
    for (int i = LCH - 1; i >= 0; --i) v = (int)((bp[i] >> (4 * v)) & 15ULL);
    cmap[c * 12 + t] = v;
  }
}

// ---------------- backtrace phase B: scan chunk maps ----------------
__global__ __launch_bounds__(256) void k_bt_scan(const int* __restrict__ cmap,
                                                 const int* __restrict__ best,
                                                 int* __restrict__ evec) {
  __shared__ int cm[NC * 12];
  __shared__ int es[NC];
  const int t = threadIdx.x;
  for (int i = t; i < NC * 12; i += 256) cm[i] = cmap[i];
  __syncthreads();
  if (t == 0) {
    int tag = best[0];
    es[NC - 1] = tag;
    for (int c = NC - 1; c >= 1; --c) { tag = cm[c * 12 + tag]; es[c - 1] = tag; }
  }
  __syncthreads();
  evec[t] = es[t];
}

// ---------------- backtrace phase C: emit path ----------------
__global__ __launch_bounds__(64) void k_bt_replay(const unsigned long long* __restrict__ bptr,
                                                  const int* __restrict__ evec,
                                                  float* __restrict__ dout) {
  __shared__ unsigned long long bp[LCH];
  __shared__ int tgs[LCH];
  const int t = threadIdx.x, c = blockIdx.x;
  if (t < LCH) bp[t] = bptr[(size_t)c * LCH + t];
  __syncthreads();
  if (t == 0) {
    int tag = evec[c];  // tag at global index (c+1)*LCH
    for (int i = LCH - 1; i >= 0; --i) {
      tgs[i] = tag;                              // out[c*LCH+i] = tag_{c*LCH+i+1}
      tag = (int)((bp[i] >> (4 * tag)) & 15ULL);
    }
  }
  __syncthreads();
  dout[1 + c * LCH + t] = (float)tgs[t];
}

// ---------------- launcher ----------------
extern "C" void kernel_launch(void* const* d_in, const int* in_sizes, int n_in,
                              void* d_out, int out_size, void* d_ws, size_t ws_size,
                              hipStream_t stream) {
  const int*   sent = (const int*)d_in[0];
  const float* emb  = (const float*)d_in[1];
  const float* wihf = (const float*)d_in[2];
  const float* whhf = (const float*)d_in[3];
  const float* bf   = (const float*)d_in[4];
  const float* wihb = (const float*)d_in[5];
  const float* whhb = (const float*)d_in[6];
  const float* bb   = (const float*)d_in[7];
  const float* h0   = (const float*)d_in[8];
  const float* c0   = (const float*)d_in[9];
  const float* Wout = (const float*)d_in[10];
  const float* bout = (const float*)d_in[11];
  const float* trans= (const float*)d_in[12];
  float* out = (float*)d_out;
  char* ws = (char*)d_ws;
  if (ws_size < WS_NEED) return;  // workspace too small: bail (visible as wrong output)

  float* xs    = (float*)(ws + OFF_XS);
  float* wT    = (float*)(ws + OFF_WT);
  float* xpf   = (float*)(ws + OFF_XPF);
  float* xpb   = (float*)(ws + OFF_XPB);
  float* hf    = (float*)(ws + OFF_HF);
  float* hb    = (float*)(ws + OFF_HB);
  float* feats = (float*)(ws + OFF_FEATS);
  float* pmat  = (float*)(ws + OFF_PMAT);
  float* fvin  = (float*)(ws + OFF_FVIN);
  unsigned long long* bptr = (unsigned long long*)(ws + OFF_BPTR);
  int*   cmap  = (int*)(ws + OFF_CMAP);
  int*   evec  = (int*)(ws + OFF_EVEC);
  int*   best  = (int*)(ws + OFF_BEST);
  float* whT   = (float*)(ws + OFF_WHT);   // overlaps xs: written after k_inproj

  hipLaunchKernelGGL(k_gather, dim3(512), dim3(256), 0, stream, sent, emb, xs);
  hipLaunchKernelGGL(k_transpose, dim3(2048), dim3(256), 0, stream, wihf, wihb, wT);
  hipLaunchKernelGGL(k_inproj, dim3(512, 8, 2), dim3(256), 0, stream,
                     xs, wT, bf, bb, xpf, xpb);
  // xs is dead now; transpose w_hh into its region for k_lstm
  hipLaunchKernelGGL(k_transpose, dim3(2048), dim3(256), 0, stream, whhf, whhb, whT);
  hipLaunchKernelGGL(k_lstm, dim3(16), dim3(1024), 0, stream,
                     whT, h0, c0, xpf, xpb, hf, hb);
  hipLaunchKernelGGL(k_feats, dim3(64), dim3(256), 0, stream, hf, hb, Wout, bout, feats);
  hipLaunchKernelGGL(k_vit_chunkmat, dim3(NC), dim3(192), 0, stream, feats, trans, pmat);
  hipLaunchKernelGGL(k_vit_scan, dim3(1), dim3(192), 0, stream, pmat, trans, fvin, out, best);
  hipLaunchKernelGGL(k_vit_replay, dim3(NC), dim3(64), 0, stream, feats, trans, fvin, bptr);
  hipLaunchKernelGGL(k_bt_chunk, dim3(NC), dim3(64), 0, stream, bptr, cmap);
  hipLaunchKernelGGL(k_bt_scan, dim3(1), dim3(256), 0, stream, cmap, best, evec);
  hipLaunchKernelGGL(k_bt_replay, dim3(NC), dim3(64), 0, stream, bptr, evec, out);
}

// Round 12
// 12961.624 us; speedup vs baseline: 1.6016x; 1.6016x over previous
//
#include <hip/hip_runtime.h>
#include <cstdint>
#include <cstddef>

// ---------------- problem constants ----------------
namespace {
constexpr int Bb = 8, Ss = 2048, Ee = 256, Hh = 256, G4 = 1024, Tt = 12;
constexpr int NTOK = Bb * Ss;              // 16384 rows
constexpr int NC = 256, LCH = 64;          // viterbi chunking: 256 chunks x 64 steps
constexpr float FNEG = -10000.0f;
constexpr int START_TAG = 10, STOP_TAG = 11;

// ---------------- workspace layout (bytes) ----------------
constexpr size_t OFF_XS    = 0;                         // [16384][256] f32 gathered embeddings
constexpr size_t SZ_XS     = (size_t)NTOK * Ee * 4;
constexpr size_t OFF_WT    = OFF_XS + SZ_XS;            // [2][256][1024] f32 w_ih transposed
constexpr size_t SZ_WT     = (size_t)2 * Ee * G4 * 4;
constexpr size_t OFF_XPF   = OFF_WT + SZ_WT;            // [2048][8][1024] f32 x-proj fwd (bias folded)
constexpr size_t SZ_XP     = (size_t)Ss * Bb * G4 * 4;
constexpr size_t OFF_XPB   = OFF_XPF + SZ_XP;
constexpr size_t OFF_HF    = OFF_XPB + SZ_XP;           // [2048][8][256] f32 fwd hidden history
constexpr size_t SZ_H      = (size_t)Ss * Bb * Hh * 4;
constexpr size_t OFF_HB    = OFF_HF + SZ_H;
constexpr size_t OFF_FEATS = OFF_HB + SZ_H;             // [16384][12] f32
constexpr size_t SZ_FEATS  = (size_t)NTOK * Tt * 4;
constexpr size_t OFF_PMAT  = OFF_FEATS + SZ_FEATS;      // [256][144] f32 chunk max-plus mats
constexpr size_t SZ_PMAT   = (size_t)NC * 144 * 4;
constexpr size_t OFF_FVIN  = OFF_PMAT + SZ_PMAT;        // [256][12] f32 chunk-entry fv
constexpr size_t SZ_FVIN   = (size_t)NC * Tt * 4;
constexpr size_t OFF_BPTR  = OFF_FVIN + SZ_FVIN;        // [16384] u64 packed 12x4bit backptrs
constexpr size_t SZ_BPTR   = (size_t)NTOK * 8;
constexpr size_t OFF_CMAP  = OFF_BPTR + SZ_BPTR;        // [256][12] int chunk composed maps
constexpr size_t SZ_CMAP   = (size_t)NC * Tt * 4;
constexpr size_t OFF_EVEC  = OFF_CMAP + SZ_CMAP;        // [256] int tag at chunk-end
constexpr size_t SZ_EVEC   = (size_t)NC * 4;
constexpr size_t OFF_BEST  = OFF_EVEC + SZ_EVEC;        // [1] int
constexpr size_t SZ_BEST   = 256;
constexpr size_t OFF_HD    = OFF_BEST + SZ_BEST;        // (legacy, unused)
constexpr size_t SZ_HD     = (size_t)2 * 2 * 2048 * 8;
constexpr size_t OFF_EPOCH = OFF_HD + SZ_HD;            // (legacy, unused)
constexpr size_t SZ_EPOCH  = 256;
constexpr size_t WS_NEED   = OFF_EPOCH + SZ_EPOCH;      // ~179 MB (unchanged)

// w_hh^T [2][256][1024] (2 MB) lives in the XS region, which is dead after
// k_inproj consumes xs. Written by a second k_transpose dispatch that runs
// AFTER k_inproj (stream-ordered), read by k_lstm via normal loads.
constexpr size_t OFF_WHT   = OFF_XS;
static_assert(2 * 256 * 1024 * 4 <= SZ_XS, "whhT fits in xs region");

// R16 k_lstm decomposition: 1024 threads = 256 column-groups (x4 cols,
// float4) x 4 k-quarters. Rate isolation from R12-R15: 4 waves + 16B loads
// = 95 GB/s/CU (R14); 16 waves + 4B loads = 90 GB/s/CU (R15); m56's 135-144
// GB/s/CU needs BOTH 16 waves and 16B/lane -- this map provides both, plus
// 4-way k-split of the FMA chain, with partials reduced through LDS.
// Weight tiers PER K-QUARTER (64 k-rows each):
//   QR=12 rows in VGPRs  (12 float4 = 48 regs/thread -- small enough that
//                         the allocator has honored arrays this size)
//   QL=8  rows in LDS    (32 rows total = 128 KB)
//   QS=44 rows streamed  (176 rows = 704 KB/step, L2-resident)
constexpr int QR = 12, QL = 8, QS = 64 - QR - QL;   // 44
constexpr int KL = 4 * QL;                          // 32 LDS rows total

__device__ __forceinline__ float4 f4fma(float a, float4 b, float4 c) {
  c.x = fmaf(a, b.x, c.x); c.y = fmaf(a, b.y, c.y);
  c.z = fmaf(a, b.z, c.z); c.w = fmaf(a, b.w, c.w);
  return c;
}
}  // namespace

// ---------------- gather embeddings: xs[r=t*8+b][k] = emb[sentence[b][t]][k] ----------------
__global__ __launch_bounds__(256) void k_gather(const int* __restrict__ sent,
                                                const float* __restrict__ emb,
                                                float* __restrict__ xs) {
  int rr = threadIdx.x >> 3, p = threadIdx.x & 7;
  int r = blockIdx.x * 32 + rr;
  int tg = r >> 3, bg = r & 7;
  int tok = sent[bg * Ss + tg];
  const float4* src = (const float4*)(emb + (size_t)tok * Ee) + p * 8;
  float4* dst = (float4*)(xs + (size_t)r * Ee) + p * 8;
#pragma unroll
  for (int i = 0; i < 8; ++i) dst[i] = src[i];
}

// ---------------- transpose [1024][256] -> [k][n] (used for w_ih AND w_hh) ----------------
__global__ __launch_bounds__(256) void k_transpose(const float* __restrict__ w_f,
                                                   const float* __restrict__ w_b,
                                                   float* __restrict__ wT) {
  int idx = blockIdx.x * 256 + threadIdx.x;
  if (idx >= 2 * Ee * G4) return;
  int d = idx >> 18;
  int rem = idx & 262143;
  int k = rem >> 10, n = rem & 1023;
  const float* w = d ? w_b : w_f;
  wT[idx] = w[n * Ee + k];
}

// ---------------- input projection GEMM: xp[r][n] = xs[r][:] . w_ih[n][:] + bias[n] ----------------
__global__ __launch_bounds__(256) void k_inproj(const float* __restrict__ xs,
                                                const float* __restrict__ wT,
                                                const float* __restrict__ b_f,
                                                const float* __restrict__ b_b,
                                                float* __restrict__ xpf,
                                                float* __restrict__ xpb) {
  const int dir = blockIdx.z;
  const float* wTd = wT + (size_t)dir * (Ee * G4);
  const float* bv = dir ? b_b : b_f;
  float* xp = dir ? xpb : xpf;
  const int rg = threadIdx.x >> 5, cg = threadIdx.x & 31;
  const int rbase = blockIdx.x * 32 + rg * 4;
  const int c0 = blockIdx.y * 128 + cg * 4;
  const float4* ap0 = (const float4*)(xs + (size_t)(rbase + 0) * Ee);
  const float4* ap1 = (const float4*)(xs + (size_t)(rbase + 1) * Ee);
  const float4* ap2 = (const float4*)(xs + (size_t)(rbase + 2) * Ee);
  const float4* ap3 = (const float4*)(xs + (size_t)(rbase + 3) * Ee);
  float4 acc0 = {0,0,0,0}, acc1 = {0,0,0,0}, acc2 = {0,0,0,0}, acc3 = {0,0,0,0};
#pragma unroll 4
  for (int k4 = 0; k4 < 64; ++k4) {
    float4 a0 = ap0[k4], a1 = ap1[k4], a2 = ap2[k4], a3 = ap3[k4];
    const float* wb = wTd + (size_t)(k4 * 4) * G4 + c0;
    float4 b0 = *(const float4*)(wb);
    float4 b1 = *(const float4*)(wb + G4);
    float4 b2 = *(const float4*)(wb + 2 * G4);
    float4 b3 = *(const float4*)(wb + 3 * G4);
    acc0 = f4fma(a0.x, b0, acc0); acc0 = f4fma(a0.y, b1, acc0);
    acc0 = f4fma(a0.z, b2, acc0); acc0 = f4fma(a0.w, b3, acc0);
    acc1 = f4fma(a1.x, b0, acc1); acc1 = f4fma(a1.y, b1, acc1);
    acc1 = f4fma(a1.z, b2, acc1); acc1 = f4fma(a1.w, b3, acc1);
    acc2 = f4fma(a2.x, b0, acc2); acc2 = f4fma(a2.y, b1, acc2);
    acc2 = f4fma(a2.z, b2, acc2); acc2 = f4fma(a2.w, b3, acc2);
    acc3 = f4fma(a3.x, b0, acc3); acc3 = f4fma(a3.y, b1, acc3);
    acc3 = f4fma(a3.z, b2, acc3); acc3 = f4fma(a3.w, b3, acc3);
  }
  float4 bias = *(const float4*)(bv + c0);
  acc0.x += bias.x; acc0.y += bias.y; acc0.z += bias.z; acc0.w += bias.w;
  acc1.x += bias.x; acc1.y += bias.y; acc1.z += bias.z; acc1.w += bias.w;
  acc2.x += bias.x; acc2.y += bias.y; acc2.z += bias.z; acc2.w += bias.w;
  acc3.x += bias.x; acc3.y += bias.y; acc3.z += bias.z; acc3.w += bias.w;
  *(float4*)(xp + (size_t)(rbase + 0) * G4 + c0) = acc0;
  *(float4*)(xp + (size_t)(rbase + 1) * G4 + c0) = acc1;
  *(float4*)(xp + (size_t)(rbase + 2) * G4 + c0) = acc2;
  *(float4*)(xp + (size_t)(rbase + 3) * G4 + c0) = acc3;
}

// ---------------- persistent bidirectional LSTM: BATCH-SPLIT, NO EXCHANGE ----------------
// 16 WGs, one per (dir, batch) chain, ZERO inter-WG communication (R4-R11:
// all cross-WG coherence paths bottom out at ~5-6.5us/step on this machine).
// h lives in LDS, c in registers. R16 thread map (see tier comment above):
// thread t: c = t&255 -> owns output columns n=4c..4c+3; kq = t>>8 -> owns
// k-quarter [kq*64, kq*64+64). Per step each thread accumulates its quarter's
// partial float4, writes zp[kq][4c..], LDS-reduce across quarters, gates.
// PyTorch gate order: z rows 0-255=i, 256-511=f, 512-767=g, 768-1023=o.
__global__ __launch_bounds__(1024, 1) void k_lstm(
    const float* __restrict__ whhT,
    const float* __restrict__ h0, const float* __restrict__ c0,
    const float* __restrict__ xpf, const float* __restrict__ xpb,
    float* __restrict__ hist_f, float* __restrict__ hist_b) {
  __shared__ __align__(16) float h_lds[256];
  __shared__ __align__(16) float zp[4][1024];     // per-quarter partials
  __shared__ __align__(16) float wlds[KL][1024];  // rows: kq*QL + i

  const int wg = blockIdx.x, dir = wg >> 3, b = wg & 7;
  const int t = threadIdx.x;
  const int cg = t & 255, kq = t >> 8;
  const int n0 = 4 * cg;
  const int kbase = kq * 64;
  const float* WT = whhT + (size_t)dir * (256 * 1024);
  const float* xp = dir ? xpb : xpf;
  float* hist = dir ? hist_b : hist_f;

  // tier 1: QR rows of this thread's k-quarter in registers (float4 each)
  float4 wreg[QR];
#pragma unroll
  for (int i = 0; i < QR; ++i)
    wreg[i] = *(const float4*)(WT + (size_t)(kbase + i) * 1024 + n0);
  // tier 2: KL rows into LDS (row r of wlds = quarter (r/QL), offset r%QL)
  for (int i = t; i < KL * 1024; i += 1024) {
    int row = i >> 10, col = i & 1023;
    int q = row / QL, ri = row - q * QL;
    wlds[row][col] = WT[(size_t)(q * 64 + QR + ri) * 1024 + col];
  }
  // state
  if (t < 256) h_lds[t] = h0[dir * 2048 + b * 256 + t];
  float c_reg = (t < 256) ? c0[dir * 2048 + b * 256 + t] : 0.0f;
  __syncthreads();

  for (int s = 0; s < Ss; ++s) {
    const int tg = dir ? (Ss - 1 - s) : s;
    // quarter 0 seeds with xp (h-independent float4 load)
    float4 acc = {0, 0, 0, 0};
    if (kq == 0)
      acc = *(const float4*)(xp + (size_t)tg * 8192 + b * 1024 + n0);
    float4 acc2 = {0, 0, 0, 0};
    // tier 1: registers
#pragma unroll
    for (int i = 0; i < QR; i += 2) {
      acc = f4fma(h_lds[kbase + i], wreg[i], acc);
      acc2 = f4fma(h_lds[kbase + i + 1], wreg[i + 1], acc2);
    }
    // tier 2: LDS
#pragma unroll
    for (int i = 0; i < QL; i += 2) {
      float4 w0 = *(const float4*)&wlds[kq * QL + i][n0];
      float4 w1 = *(const float4*)&wlds[kq * QL + i + 1][n0];
      acc = f4fma(h_lds[kbase + QR + i], w0, acc);
      acc2 = f4fma(h_lds[kbase + QR + i + 1], w1, acc2);
    }
    // tier 3: streamed from L2 -- 16 waves x 16B/lane, fully coalesced
    {
      const float* wp = WT + (size_t)(kbase + QR + QL) * 1024 + n0;
      const float* hp = &h_lds[kbase + QR + QL];
#pragma unroll 4
      for (int i = 0; i < QS; i += 2) {
        float4 w0 = *(const float4*)(wp + (size_t)i * 1024);
        float4 w1 = *(const float4*)(wp + (size_t)(i + 1) * 1024);
        acc = f4fma(hp[i], w0, acc);
        acc2 = f4fma(hp[i + 1], w1, acc2);
      }
    }
    acc.x += acc2.x; acc.y += acc2.y; acc.z += acc2.z; acc.w += acc2.w;
    *(float4*)&zp[kq][n0] = acc;
    __syncthreads();  // B1: partials complete; h_lds reads of this step done
    // cross-quarter reduce: thread t owns column t
    {
      float z = zp[0][t] + zp[1][t] + zp[2][t] + zp[3][t];
      zp[0][t] = z;
    }
    __syncthreads();  // B1b: z final in zp[0]
    if (t < 256) {
      float zi = zp[0][t], zf = zp[0][256 + t];
      float zg = zp[0][512 + t], zo = zp[0][768 + t];
      float iv = 1.0f / (1.0f + expf(-zi));
      float fv = 1.0f / (1.0f + expf(-zf));
      float gv = tanhf(zg);
      float ov = 1.0f / (1.0f + expf(-zo));
      c_reg = fv * c_reg + iv * gv;
      float hv = ov * tanhf(c_reg);
      h_lds[t] = hv;
      hist[(size_t)tg * 2048 + b * 256 + t] = hv;
    }
    __syncthreads();  // B2: h_{s} ready for next step
  }
}

// ---------------- feats = [hf|hb] @ W_out^T + b_out ----------------
__global__ __launch_bounds__(256) void k_feats(const float* __restrict__ hist_f,
                                               const float* __restrict__ hist_b,
                                               const float* __restrict__ Wout,
                                               const float* __restrict__ bout,
                                               float* __restrict__ feats) {
  __shared__ float wsh[Tt * 512];
  __shared__ float bsh[Tt];
  for (int i = threadIdx.x; i < Tt * 512; i += 256) wsh[i] = Wout[i];
  if (threadIdx.x < Tt) bsh[threadIdx.x] = bout[threadIdx.x];
  __syncthreads();
  int r = blockIdx.x * 256 + threadIdx.x;
  int bq = r >> 11, sq = r & 2047;
  const float4* hf4 = (const float4*)(hist_f + (size_t)sq * 2048 + bq * Hh);
  const float4* hb4 = (const float4*)(hist_b + (size_t)sq * 2048 + bq * Hh);
  float acc[Tt];
#pragma unroll
  for (int j = 0; j < Tt; ++j) acc[j] = bsh[j];
  for (int k4 = 0; k4 < 64; ++k4) {
    float4 x = hf4[k4];
#pragma unroll
    for (int j = 0; j < Tt; ++j) {
      float4 w = *(const float4*)&wsh[j * 512 + k4 * 4];
      acc[j] = fmaf(x.x, w.x, fmaf(x.y, w.y, fmaf(x.z, w.z, fmaf(x.w, w.w, acc[j]))));
    }
  }
  for (int k4 = 0; k4 < 64; ++k4) {
    float4 x = hb4[k4];
#pragma unroll
    for (int j = 0; j < Tt; ++j) {
      float4 w = *(const float4*)&wsh[j * 512 + 256 + k4 * 4];
      acc[j] = fmaf(x.x, w.x, fmaf(x.y, w.y, fmaf(x.z, w.z, fmaf(x.w, w.w, acc[j]))));
    }
  }
#pragma unroll
  for (int j = 0; j < Tt; ++j) feats[(size_t)r * Tt + j] = acc[j];
}

// ---------------- Viterbi phase 1: per-chunk max-plus matrix product ----------------
__global__ __launch_bounds__(192) void k_vit_chunkmat(const float* __restrict__ feats,
                                                      const float* __restrict__ trans,
                                                      float* __restrict__ pmat) {
  __shared__ float R[2][144];
  __shared__ float fe[LCH * Tt];
  __shared__ float ts[144];
  const int t = threadIdx.x, c = blockIdx.x;
  for (int i = t; i < LCH * Tt; i += 192) fe[i] = feats[(size_t)c * LCH * Tt + i];
  if (t < 144) ts[t] = trans[t];
  __syncthreads();
  int j = 0, k = 0;
  float trow[12];
  if (t < 144) {
    j = t / 12; k = t - j * 12;
#pragma unroll
    for (int m = 0; m < 12; ++m) trow[m] = ts[j * 12 + m];
    R[0][t] = ts[t] + fe[j];  // A_{t0}
  }
  __syncthreads();
  for (int i = 1; i < LCH; ++i) {
    int p = (i - 1) & 1;
    if (t < 144) {
      float m = trow[0] + R[p][k];
#pragma unroll
      for (int mm = 1; mm < 12; ++mm) m = fmaxf(m, trow[mm] + R[p][mm * 12 + k]);
      R[p ^ 1][t] = m + fe[i * 12 + j];
    }
    __syncthreads();
  }
  if (t < 144) pmat[(size_t)c * 144 + t] = R[(LCH - 1) & 1][t];
}

// ---------------- Viterbi phase 2: sequential scan over chunk matrices ----------------
__global__ __launch_bounds__(192) void k_vit_scan(const float* __restrict__ pmat,
                                                  const float* __restrict__ trans,
                                                  float* __restrict__ fvin,
                                                  float* __restrict__ dout,
                                                  int* __restrict__ best) {
  __shared__ float fv[12];
  __shared__ float sl[144];
  __shared__ float term[12];
  const int t = threadIdx.x;
  const int j = t / 12, k = t - j * 12;
  if (t < 12) fv[t] = (t == START_TAG) ? 0.0f : FNEG;
  float pv = (t < 144) ? pmat[t] : 0.0f;
  __syncthreads();
  for (int c = 0; c < NC; ++c) {
    if (t < 12) fvin[c * 12 + t] = fv[t];
    float pnext = (t < 144 && c + 1 < NC) ? pmat[(size_t)(c + 1) * 144 + t] : 0.0f;
    if (t < 144) sl[t] = pv + fv[k];
    __syncthreads();
    if (t < 12) {
      float m = sl[t * 12];
#pragma unroll
      for (int kk = 1; kk < 12; ++kk) m = fmaxf(m, sl[t * 12 + kk]);
      fv[t] = m;
    }
    __syncthreads();
    pv = pnext;
  }
  if (t < 12) term[t] = fv[t] + trans[STOP_TAG * 12 + t];
  __syncthreads();
  if (t == 0) {
    float m = term[0]; int a = 0;
    for (int q = 1; q < 12; ++q) { if (term[q] > m) { m = term[q]; a = q; } }
    dout[0] = m;
    best[0] = a;
  }
}

// ---------------- Viterbi phase 3: replay chunks -> packed backpointers ----------------
__global__ __launch_bounds__(64) void k_vit_replay(const float* __restrict__ feats,
                                                   const float* __restrict__ trans,
                                                   const float* __restrict__ fvin,
                                                   unsigned long long* __restrict__ bptr) {
  __shared__ float fe[LCH * Tt];
  __shared__ float fv[12];
  __shared__ int bpn[12];
  const int t = threadIdx.x, c = blockIdx.x;
  for (int i = t; i < LCH * Tt; i += 64) fe[i] = feats[(size_t)c * LCH * Tt + i];
  float trow[12];
  if (t < 12) {
#pragma unroll
    for (int m = 0; m < 12; ++m) trow[m] = trans[t * 12 + m];
    fv[t] = fvin[c * 12 + t];
  }
  __syncthreads();
  for (int i = 0; i < LCH; ++i) {
    float nm = 0.0f;
    if (t < 12) {
      float m = fv[0] + trow[0]; int a = 0;
#pragma unroll
      for (int k = 1; k < 12; ++k) {
        float v = fv[k] + trow[k];
        if (v > m) { m = v; a = k; }   // first-max wins, matches jnp.argmax
      }
      nm = m + fe[i * 12 + t];
      bpn[t] = a;
    }
    __syncthreads();
    if (t < 12) fv[t] = nm;
    if (t == 0) {
      unsigned long long bp = 0;
#pragma unroll
      for (int jq = 0; jq < 12; ++jq)
        bp |= (unsigned long long)(unsigned)bpn[jq] << (4 * jq);
      bptr[(size_t)c * LCH + i] = bp;
    }
    __syncthreads();
  }
}

// ---------------- backtrace phase A: compose per-chunk tag maps ----------------
__global__ __launch_bounds__(64) void k_bt_chunk(const unsigned long long* __restrict__ bptr,
                                                 int* __restrict__ cmap) {
  __shared__ unsigned long long bp[LCH];
  const int t = threadIdx.x, c = blockIdx.x;
  if (t < LCH) bp[t] = bptr[(size_t)c * LCH + t];
  __syncthreads();
  if (t < 12) {
    int v = t;
    for (int i = LCH - 1; i >= 0; --i) v = (int)((bp[i] >> (4 * v)) & 15ULL);
    cmap[c * 12 + t] = v;
  }
}

// ---------------- backtrace phase B: scan chunk maps ----------------
__global__ __launch_bounds__(256) void k_bt_scan(const int* __restrict__ cmap,
                                                 const int* __restrict__ best,
                                                 int* __restrict__ evec) {
  __shared__ int cm[NC * 12];
  __shared__ int es[NC];
  const int t = threadIdx.x;
  for (int i = t; i < NC * 12; i += 256) cm[i] = cmap[i];
  __syncthreads();
  if (t == 0) {
    int tag = best[0];
    es[NC - 1] = tag;
    for (int c = NC - 1; c >= 1; --c) { tag = cm[c * 12 + tag]; es[c - 1] = tag; }
  }
  __syncthreads();
  evec[t] = es[t];
}

// ---------------- backtrace phase C: emit path ----------------
__global__ __launch_bounds__(64) void k_bt_replay(const unsigned long long* __restrict__ bptr,
                                                  const int* __restrict__ evec,
                                                  float* __restrict__ dout) {
  __shared__ unsigned long long bp[LCH];
  __shared__ int tgs[LCH];
  const int t = threadIdx.x, c = blockIdx.x;
  if (t < LCH) bp[t] = bptr[(size_t)c * LCH + t];
  __syncthreads();
  if (t == 0) {
    int tag = evec[c];  // tag at global index (c+1)*LCH
    for (int i = LCH - 1; i >= 0; --i) {
      tgs[i] = tag;                              // out[c*LCH+i] = tag_{c*LCH+i+1}
      tag = (int)((bp[i] >> (4 * tag)) & 15ULL);
    }
  }
  __syncthreads();
  dout[1 + c * LCH + t] = (float)tgs[t];
}

// ---------------- launcher ----------------
extern "C" void kernel_launch(void* const* d_in, const int* in_sizes, int n_in,
                              void* d_out, int out_size, void* d_ws, size_t ws_size,
                              hipStream_t stream) {
  const int*   sent = (const int*)d_in[0];
  const float* emb  = (const float*)d_in[1];
  const float* wihf = (const float*)d_in[2];
  const float* whhf = (const float*)d_in[3];
  const float* bf   = (const float*)d_in[4];
  const float* wihb = (const float*)d_in[5];
  const float* whhb = (const float*)d_in[6];
  const float* bb   = (const float*)d_in[7];
  const float* h0   = (const float*)d_in[8];
  const float* c0   = (const float*)d_in[9];
  const float* Wout = (const float*)d_in[10];
  const float* bout = (const float*)d_in[11];
  const float* trans= (const float*)d_in[12];
  float* out = (float*)d_out;
  char* ws = (char*)d_ws;
  if (ws_size < WS_NEED) return;  // workspace too small: bail (visible as wrong output)

  float* xs    = (float*)(ws + OFF_XS);
  float* wT    = (float*)(ws + OFF_WT);
  float* xpf   = (float*)(ws + OFF_XPF);
  float* xpb   = (float*)(ws + OFF_XPB);
  float* hf    = (float*)(ws + OFF_HF);
  float* hb    = (float*)(ws + OFF_HB);
  float* feats = (float*)(ws + OFF_FEATS);
  float* pmat  = (float*)(ws + OFF_PMAT);
  float* fvin  = (float*)(ws + OFF_FVIN);
  unsigned long long* bptr = (unsigned long long*)(ws + OFF_BPTR);
  int*   cmap  = (int*)(ws + OFF_CMAP);
  int*   evec  = (int*)(ws + OFF_EVEC);
  int*   best  = (int*)(ws + OFF_BEST);
  float* whT   = (float*)(ws + OFF_WHT);   // overlaps xs: written after k_inproj

  hipLaunchKernelGGL(k_gather, dim3(512), dim3(256), 0, stream, sent, emb, xs);
  hipLaunchKernelGGL(k_transpose, dim3(2048), dim3(256), 0, stream, wihf, wihb, wT);
  hipLaunchKernelGGL(k_inproj, dim3(512, 8, 2), dim3(256), 0, stream,
                     xs, wT, bf, bb, xpf, xpb);
  // xs is dead now; transpose w_hh into its region for k_lstm
  hipLaunchKernelGGL(k_transpose, dim3(2048), dim3(256), 0, stream, whhf, whhb, whT);
  hipLaunchKernelGGL(k_lstm, dim3(16), dim3(1024), 0, stream,
                     whT, h0, c0, xpf, xpb, hf, hb);
  hipLaunchKernelGGL(k_feats, dim3(64), dim3(256), 0, stream, hf, hb, Wout, bout, feats);
  hipLaunchKernelGGL(k_vit_chunkmat, dim3(NC), dim3(192), 0, stream, feats, trans, pmat);
  hipLaunchKernelGGL(k_vit_scan, dim3(1), dim3(192), 0, stream, pmat, trans, fvin, out, best);
  hipLaunchKernelGGL(k_vit_replay, dim3(NC), dim3(64), 0, stream, feats, trans, fvin, bptr);
  hipLaunchKernelGGL(k_bt_chunk, dim3(NC), dim3(64), 0, stream, bptr, cmap);
  hipLaunchKernelGGL(k_bt_scan, dim3(1), dim3(256), 0, stream, cmap, best, evec);
  hipLaunchKernelGGL(k_bt_replay, dim3(NC), dim3(64), 0, stream, bptr, evec, out);
}